// Round 5
// baseline (367.234 us; speedup 1.0000x reference)
//
#include <hip/hip_runtime.h>

// FeatNeighbourCorr: feats [B=8, C=128, H=256, W=256] fp32 -> out [B,8,H,W] fp32.
// out[b,k,h,w] = dot_k(h,w) * rsqrt(ssq(h,w)) * rsqrt(ssq(neighbor_k))
//
// R5: LDS-staged 4-row blocks to capture the 3x row reuse INSIDE the block
// (R4's 1-row blocks re-fetched every row ~3x from HBM: 768 MB -> HBM-bound).
// Block = 512 thr = 8 waves: r = wy&3 (row), cs = wy>>2 (channel half, 64 ch).
// Per channel: 6 rows (4 + 2 halo, reflect-resolved) staged into
// double-buffered LDS; wave (r,cs) reads rows r,r+1,r+2 (= h-1,h,h+1) as
// float4 and runs the R4 register compute (3 shfl_down, boundary-symmetry
// trick, merged k2/k6 boundary term). Channel-halves reduce 44 accs via LDS
// at the end; cs==0 wave does the R4 epilogue. Fetch: 6/4 x 256 = 384 MB.

#define BB 8
#define CC 128
#define HH 256
#define WW 256
#define RR 4
#define NV 6           // staged rows per channel = RR + 2
#define CPH (CC / 2)   // 64 channels per half

#define DD(k, j) acc[12 + (k)*4 + (j)]

union SmemU {
  float stage[2][2][NV][WW];  // [buf][half][vrow][col] = 24 KB
  float red[RR][44][64];      // cross-half reduction  = 44 KB
};

__global__ __launch_bounds__(512) void featcorr_kernel(
    const float* __restrict__ feats, float* __restrict__ out) {
  __shared__ SmemU sm;
  const int lane = threadIdx.x;  // 0..63
  const int wy = threadIdx.y;    // 0..7
  const int r = wy & 3;          // row within block
  const int cs = wy >> 2;        // channel half
  const int bx = blockIdx.x;     // 0..63
  // XCD strip swizzle: XCD k gets 8 consecutive 4-row blocks (halo overlap in L2)
  const int h0 = (((bx & 7) << 3) | (bx >> 3)) * RR;
  const int b = blockIdx.y;
  const int h = h0 + r;

  const size_t HW = (size_t)HH * WW;
  const int col0 = lane * 4;

  // Staged virtual rows v=0..5 hold global row reflect(h0-1+v).
  // Wave r stages v=r; waves r<2 additionally stage v=4+r.
  int g1 = h0 - 1 + r;
  if (g1 < 0) g1 = 1;            // h0==0, r==0
  const bool two = (r < 2);
  int g2 = h0 + 3 + r;           // v = 4+r  ->  h0-1+4+r
  if (g2 >= HH) g2 = HH - 2;     // h0==252, r==1

  const float* base = feats + ((size_t)b * CC + (size_t)cs * CPH) * HW + col0;
  const float* p1 = base + (size_t)g1 * WW;
  const float* p2 = base + (size_t)g2 * WW;

  float acc[44];
#pragma unroll
  for (int a = 0; a < 44; ++a) acc[a] = 0.f;

  auto gload = [&](int c, float4& a1, float4& a2) {
    a1 = *(const float4*)(p1 + (size_t)c * HW);
    if (two) a2 = *(const float4*)(p2 + (size_t)c * HW);
  };
  auto stage = [&](int buf, const float4 a1, const float4 a2) {
    *(float4*)&sm.stage[buf][cs][r][col0] = a1;
    if (two) *(float4*)&sm.stage[buf][cs][4 + r][col0] = a2;
  };

  auto compute = [&](int buf) {
    const float4 t = *(const float4*)&sm.stage[buf][cs][r][col0];      // row h-1
    const float4 m = *(const float4*)&sm.stage[buf][cs][r + 1][col0];  // row h
    const float4 bt = *(const float4*)&sm.stage[buf][cs][r + 2][col0]; // row h+1
    const float rT = __shfl_down(t.x, 1);
    const float rM = __shfl_down(m.x, 1);
    const float rB = __shfl_down(bt.x, 1);
    acc[0] += t.x * t.x;  acc[1] += t.y * t.y;  acc[2] += t.z * t.z;  acc[3] += t.w * t.w;
    acc[4] += m.x * m.x;  acc[5] += m.y * m.y;  acc[6] += m.z * m.z;  acc[7] += m.w * m.w;
    acc[8] += bt.x * bt.x; acc[9] += bt.y * bt.y; acc[10] += bt.z * bt.z; acc[11] += bt.w * bt.w;
    DD(0, 0) += m.x * t.x; DD(0, 1) += m.y * t.y; DD(0, 2) += m.z * t.z; DD(0, 3) += m.w * t.w;
    DD(4, 0) += m.x * bt.x; DD(4, 1) += m.y * bt.y; DD(4, 2) += m.z * bt.z; DD(4, 3) += m.w * bt.w;
    DD(1, 1) += m.y * t.x; DD(1, 2) += m.z * t.y; DD(1, 3) += m.w * t.z;
    DD(1, 0) += rM * t.w;
    DD(2, 1) += m.y * m.x; DD(2, 2) += m.z * m.y; DD(2, 3) += m.w * m.z;
    DD(3, 1) += m.y * bt.x; DD(3, 2) += m.z * bt.y; DD(3, 3) += m.w * bt.z;
    DD(3, 0) += rM * bt.w;
    DD(5, 0) += m.x * bt.y; DD(5, 1) += m.y * bt.z; DD(5, 2) += m.z * bt.w; DD(5, 3) += m.w * rB;
    DD(6, 0) += m.x * m.y; DD(6, 1) += m.y * m.z; DD(6, 2) += m.z * m.w; DD(6, 3) += m.w * rM;
    DD(7, 0) += m.x * t.y; DD(7, 1) += m.y * t.z; DD(7, 2) += m.z * t.w; DD(7, 3) += m.w * rT;
  };

  // ---- prologue: stage c=0, preload c=1 ----
  float4 s0a, s0b = make_float4(0, 0, 0, 0);
  float4 s1a, s1b = make_float4(0, 0, 0, 0);
  gload(0, s0a, s0b);
  gload(1, s1a, s1b);
  stage(0, s0a, s0b);
  __syncthreads();

  // ---- double-buffered channel loop (2-channel load lookahead) ----
  for (int c = 0; c < CPH; c += 2) {
    // even: compute c (buf0), stage c+1 (buf1) from s1, load c+2 -> s0
    if (c + 2 < CPH) gload(c + 2, s0a, s0b);
    stage(1, s1a, s1b);
    compute(0);
    __syncthreads();
    // odd: compute c+1 (buf1), stage c+2 (buf0) from s0, load c+3 -> s1
    if (c + 3 < CPH) gload(c + 3, s1a, s1b);
    if (c + 2 < CPH) stage(0, s0a, s0b);
    compute(1);
    __syncthreads();
  }

  // ---- cross-half reduction (union reuse of staging LDS) ----
  if (cs == 1) {
#pragma unroll
    for (int a = 0; a < 44; ++a) sm.red[r][a][lane] = acc[a];
  }
  __syncthreads();

  if (cs == 0) {
#pragma unroll
    for (int a = 0; a < 44; ++a) acc[a] += sm.red[r][a][lane];

    // deliver left-lane boundary dots; reflect edges via symmetry
    const float g1v = __shfl_up(DD(1, 0), 1);
    const float g2v = __shfl_up(DD(6, 3), 1);  // merged k2 boundary
    const float g3v = __shfl_up(DD(3, 0), 1);
    DD(1, 0) = (lane == 0) ? DD(7, 0) : g1v;
    DD(2, 0) = (lane == 0) ? DD(6, 0) : g2v;
    DD(3, 0) = (lane == 0) ? DD(5, 0) : g3v;
    if (lane == 63) {
      DD(5, 3) = DD(3, 3);
      DD(6, 3) = DD(2, 3);
      DD(7, 3) = DD(1, 3);
    }

    float it[4], im[4], ib[4];
#pragma unroll
    for (int j = 0; j < 4; ++j) {
      it[j] = rsqrtf(acc[j]);
      im[j] = rsqrtf(acc[4 + j]);
      ib[j] = rsqrtf(acc[8 + j]);
    }
    float IT[6], IM[6], IB[6];
    IT[1] = it[0]; IT[2] = it[1]; IT[3] = it[2]; IT[4] = it[3];
    IM[1] = im[0]; IM[2] = im[1]; IM[3] = im[2]; IM[4] = im[3];
    IB[1] = ib[0]; IB[2] = ib[1]; IB[3] = ib[2]; IB[4] = ib[3];
    const float tl = __shfl_up(it[3], 1), ml = __shfl_up(im[3], 1), bl = __shfl_up(ib[3], 1);
    const float tr = __shfl_down(it[0], 1), mr = __shfl_down(im[0], 1), br = __shfl_down(ib[0], 1);
    IT[0] = (lane == 0) ? it[1] : tl;
    IM[0] = (lane == 0) ? im[1] : ml;
    IB[0] = (lane == 0) ? ib[1] : bl;
    IT[5] = (lane == 63) ? it[2] : tr;
    IM[5] = (lane == 63) ? im[2] : mr;
    IB[5] = (lane == 63) ? ib[2] : br;

    float* obase = out + ((size_t)b * 8) * HW + (size_t)h * WW + col0;
#pragma unroll
    for (int k = 0; k < 8; ++k) {
      float v[4];
#pragma unroll
      for (int j = 0; j < 4; ++j) {
        float in;
        switch (k) {
          case 0: in = it[j];     break;  // (h-1, w)
          case 1: in = IT[j];     break;  // (h-1, w-1)
          case 2: in = IM[j];     break;  // (h,   w-1)
          case 3: in = IB[j];     break;  // (h+1, w-1)
          case 4: in = ib[j];     break;  // (h+1, w)
          case 5: in = IB[j + 2]; break;  // (h+1, w+1)
          case 6: in = IM[j + 2]; break;  // (h,   w+1)
          default: in = IT[j + 2]; break; // (h-1, w+1)
        }
        v[j] = DD(k, j) * im[j] * in;
      }
      float4 o;
      o.x = v[0]; o.y = v[1]; o.z = v[2]; o.w = v[3];
      *(float4*)(obase + (size_t)k * HW) = o;
    }
  }
}

extern "C" void kernel_launch(void* const* d_in, const int* in_sizes, int n_in,
                              void* d_out, int out_size, void* d_ws, size_t ws_size,
                              hipStream_t stream) {
  const float* feats = (const float*)d_in[0];
  float* out = (float*)d_out;
  dim3 block(64, 8, 1);
  dim3 grid(HH / RR, BB, 1);
  featcorr_kernel<<<grid, block, 0, stream>>>(feats, out);
}

// Round 6
// 364.772 us; speedup vs baseline: 1.0068x; 1.0068x over previous
//
#include <hip/hip_runtime.h>

// FeatNeighbourCorr: feats [B=8, C=128, H=256, W=256] fp32 -> out [B,8,H,W] fp32.
// out[b,k,h,w] = dot_k(h,w) * rsqrt(ssq(h,w)) * rsqrt(ssq(neighbor_k))
//
// R6: 2 OUTPUT ROWS PER WAVE (rows h0, h0+1 from 4 loaded rows h0-1..h0+2)
// -> read traffic 2 rows per output row instead of 3: 768 -> 512 MB total.
// Barrier-free R4 structure otherwise: lane owns 4 cols (float4), right
// neighbor via shfl_down, left-boundary dot terms accumulated by the left
// lane + one shfl_up at the end, reflect edges by symmetry. Channel-split 2
// (64 ch/wave), one LDS reduction + single barrier. 8 waves/CU.

#define BB 8
#define CC 128
#define HH 256
#define WW 256
#define CPH (CC / 2)  // 64 channels per half

// dot accumulators for one output row at acc[BASE + k*4 + j]
#define DOTS(BASE, up, mid, dn, rU, rM_, rD)                                 \
  {                                                                          \
    acc[BASE+0]  += mid.x*up.x;  acc[BASE+1]  += mid.y*up.y;   /* k0 */      \
    acc[BASE+2]  += mid.z*up.z;  acc[BASE+3]  += mid.w*up.w;                 \
    acc[BASE+5]  += mid.y*up.x;  acc[BASE+6]  += mid.z*up.y;   /* k1 */      \
    acc[BASE+7]  += mid.w*up.z;  acc[BASE+4]  += rM_*up.w;                   \
    acc[BASE+9]  += mid.y*mid.x; acc[BASE+10] += mid.z*mid.y;  /* k2 */      \
    acc[BASE+11] += mid.w*mid.z; /* k2 boundary merged into k6 slot */       \
    acc[BASE+13] += mid.y*dn.x;  acc[BASE+14] += mid.z*dn.y;   /* k3 */      \
    acc[BASE+15] += mid.w*dn.z;  acc[BASE+12] += rM_*dn.w;                   \
    acc[BASE+16] += mid.x*dn.x;  acc[BASE+17] += mid.y*dn.y;   /* k4 */      \
    acc[BASE+18] += mid.z*dn.z;  acc[BASE+19] += mid.w*dn.w;                 \
    acc[BASE+20] += mid.x*dn.y;  acc[BASE+21] += mid.y*dn.z;   /* k5 */      \
    acc[BASE+22] += mid.z*dn.w;  acc[BASE+23] += mid.w*rD;                   \
    acc[BASE+24] += mid.x*mid.y; acc[BASE+25] += mid.y*mid.z;  /* k6 */      \
    acc[BASE+26] += mid.z*mid.w; acc[BASE+27] += mid.w*rM_;                  \
    acc[BASE+28] += mid.x*up.y;  acc[BASE+29] += mid.y*up.z;   /* k7 */      \
    acc[BASE+30] += mid.z*up.w;  acc[BASE+31] += mid.w*rU;                   \
  }

// boundary fix for one output row (post-reduction)
#define FIXB(Dbase)                                                          \
  {                                                                          \
    const float g1 = __shfl_up(acc[Dbase+4],  1);                            \
    const float g2 = __shfl_up(acc[Dbase+27], 1); /* merged k2 boundary */   \
    const float g3 = __shfl_up(acc[Dbase+12], 1);                            \
    acc[Dbase+4]  = (lane == 0) ? acc[Dbase+28] : g1;                        \
    acc[Dbase+8]  = (lane == 0) ? acc[Dbase+24] : g2;                        \
    acc[Dbase+12] = (lane == 0) ? acc[Dbase+20] : g3;                        \
    if (lane == 63) {                                                        \
      acc[Dbase+23] = acc[Dbase+15];                                         \
      acc[Dbase+27] = acc[Dbase+11];                                         \
      acc[Dbase+31] = acc[Dbase+7];                                          \
    }                                                                        \
  }

// extended inv-norm array over cols [col0-1 .. col0+4]
#define EXT(e, ip)                                                           \
  {                                                                          \
    e[1] = ip[0]; e[2] = ip[1]; e[3] = ip[2]; e[4] = ip[3];                  \
    const float l = __shfl_up(ip[3], 1);                                     \
    const float r = __shfl_down(ip[0], 1);                                   \
    e[0] = (lane == 0) ? ip[1] : l;                                          \
    e[5] = (lane == 63) ? ip[2] : r;                                         \
  }

// emit one k-plane of 4 px for output row with dots at Dbase, center ext eC,
// neighbor array `arr` at column offset `off`
#define EMIT_K(k, arr, off)                                                  \
  {                                                                          \
    float4 o;                                                                \
    o.x = acc[Dbase+(k)*4+0] * eC[1] * arr[0+off];                           \
    o.y = acc[Dbase+(k)*4+1] * eC[2] * arr[1+off];                           \
    o.z = acc[Dbase+(k)*4+2] * eC[3] * arr[2+off];                           \
    o.w = acc[Dbase+(k)*4+3] * eC[4] * arr[3+off];                           \
    *(float4*)(obase + (size_t)(k)*HW) = o;                                  \
  }

__global__ __launch_bounds__(128) void featcorr_kernel(
    const float* __restrict__ feats, float* __restrict__ out) {
  const int lane = threadIdx.x;  // 0..63
  const int cs = threadIdx.y;    // 0..1 channel half
  const int bx = blockIdx.x;     // 0..127
  // XCD strip swizzle: 16 consecutive blocks (32 rows) per XCD strip
  const int h0 = (((bx & 7) << 4) | (bx >> 3)) * 2;
  const int b = blockIdx.y;

  const int gT = (h0 == 0) ? 1 : h0 - 1;                 // reflect(h0-1)
  const int gB = (h0 + 2 >= HH) ? HH - 2 : h0 + 2;       // reflect(h0+2)

  const size_t HW = (size_t)HH * WW;
  const int col0 = lane * 4;

  const float* base = feats + ((size_t)b * CC + (size_t)cs * CPH) * HW + col0;
  const float* pT = base + (size_t)gT * WW;
  const float* pM = base + (size_t)h0 * WW;
  const float* pN = base + (size_t)(h0 + 1) * WW;
  const float* pB = base + (size_t)gB * WW;

  // acc layout: [0..3]=ssq row h0-1, [4..7]=row h0, [8..11]=row h0+1,
  // [12..15]=row h0+2, [16..47]=dots row h0, [48..79]=dots row h0+1
  float acc[80];
#pragma unroll
  for (int a = 0; a < 80; ++a) acc[a] = 0.f;

#pragma unroll 4
  for (int c = 0; c < CPH; ++c) {
    const float4 t  = *(const float4*)pT; pT += HW;
    const float4 m  = *(const float4*)pM; pM += HW;
    const float4 n  = *(const float4*)pN; pN += HW;
    const float4 bt = *(const float4*)pB; pB += HW;
    const float rT = __shfl_down(t.x, 1);
    const float rM = __shfl_down(m.x, 1);
    const float rN = __shfl_down(n.x, 1);
    const float rB = __shfl_down(bt.x, 1);
    acc[0]  += t.x*t.x;   acc[1]  += t.y*t.y;   acc[2]  += t.z*t.z;   acc[3]  += t.w*t.w;
    acc[4]  += m.x*m.x;   acc[5]  += m.y*m.y;   acc[6]  += m.z*m.z;   acc[7]  += m.w*m.w;
    acc[8]  += n.x*n.x;   acc[9]  += n.y*n.y;   acc[10] += n.z*n.z;   acc[11] += n.w*n.w;
    acc[12] += bt.x*bt.x; acc[13] += bt.y*bt.y; acc[14] += bt.z*bt.z; acc[15] += bt.w*bt.w;
    DOTS(16, t, m, n, rT, rM, rN);   // output row h0:   up=t, mid=m, dn=n
    DOTS(48, m, n, bt, rM, rN, rB);  // output row h0+1: up=m, mid=n, dn=bt
  }

  // ---- cross-half reduction (20 KB LDS, one barrier) ----
  __shared__ float red[80][64];
  if (cs == 1) {
#pragma unroll
    for (int a = 0; a < 80; ++a) red[a][lane] = acc[a];
  }
  __syncthreads();

  if (cs == 0) {
#pragma unroll
    for (int a = 0; a < 80; ++a) acc[a] += red[a][lane];

    FIXB(16);
    FIXB(48);

    float iT[4], iM[4], iN[4], iB[4];
#pragma unroll
    for (int j = 0; j < 4; ++j) {
      iT[j] = rsqrtf(acc[j]);
      iM[j] = rsqrtf(acc[4 + j]);
      iN[j] = rsqrtf(acc[8 + j]);
      iB[j] = rsqrtf(acc[12 + j]);
    }
    float eT[6], eM[6], eN[6], eB[6];
    EXT(eT, iT); EXT(eM, iM); EXT(eN, iN); EXT(eB, iB);

    {  // output row h0: up=eT, center=eM, dn=eN
      const int Dbase = 16;
      const float* eC = eM;
      float* obase = out + ((size_t)b * 8) * HW + (size_t)h0 * WW + col0;
      EMIT_K(0, eT, 1) EMIT_K(1, eT, 0) EMIT_K(2, eM, 0) EMIT_K(3, eN, 0)
      EMIT_K(4, eN, 1) EMIT_K(5, eN, 2) EMIT_K(6, eM, 2) EMIT_K(7, eT, 2)
    }
    {  // output row h0+1: up=eM, center=eN, dn=eB
      const int Dbase = 48;
      const float* eC = eN;
      float* obase = out + ((size_t)b * 8) * HW + (size_t)(h0 + 1) * WW + col0;
      EMIT_K(0, eM, 1) EMIT_K(1, eM, 0) EMIT_K(2, eN, 0) EMIT_K(3, eB, 0)
      EMIT_K(4, eB, 1) EMIT_K(5, eB, 2) EMIT_K(6, eN, 2) EMIT_K(7, eM, 2)
    }
  }
}

extern "C" void kernel_launch(void* const* d_in, const int* in_sizes, int n_in,
                              void* d_out, int out_size, void* d_ws, size_t ws_size,
                              hipStream_t stream) {
  const float* feats = (const float*)d_in[0];
  float* out = (float*)d_out;
  dim3 block(64, 2, 1);
  dim3 grid(HH / 2, BB, 1);
  featcorr_kernel<<<grid, block, 0, stream>>>(feats, out);
}